// Round 10
// baseline (158.968 us; speedup 1.0000x reference)
//
#include <hip/hip_runtime.h>
#include <math.h>

#define N_ 8192
#define D_ 512
#define NC_ 128
#define T32 32     // 8192/256 row-tiles
#define BK_ 64     // K-step
#define KSTEPS 8   // 512/64

typedef __attribute__((ext_vector_type(8))) short bf16x8;
typedef __attribute__((ext_vector_type(4))) float f32x4;
typedef __attribute__((ext_vector_type(4))) unsigned short us4;

static __device__ __forceinline__ unsigned short f2bf(float f) {
    union { float f; unsigned u; } c; c.f = f;
    unsigned u = c.u;
    u += 0x7fffu + ((u >> 16) & 1u);   // round-to-nearest-even
    return (unsigned short)(u >> 16);
}

// ---------- kernel 1: convert + last-row fp64 dots + histogram (wide) --------
__global__ __launch_bounds__(256) void k_pre(const float* __restrict__ x,
                                             unsigned short* __restrict__ xb,
                                             const int* __restrict__ tg,
                                             double* __restrict__ sim_last,
                                             int* __restrict__ hist32,
                                             double* __restrict__ gd,
                                             int* __restrict__ gi) {
    const int bid = blockIdx.x;
    const int tid = threadIdx.x;
    if (bid == 0 && tid == 0) {
        atomicExch((unsigned long long*)&gd[0], 0ull);
        atomicExch((unsigned long long*)&gd[1], 0ull);
        atomicExch((unsigned long long*)&gd[2], 0ull);
        atomicExch(&gi[0], 0); atomicExch(&gi[1], 0);
        atomicExch(&gi[2], 0); atomicExch(&gi[3], 0);
    }
    if (bid < 4096) {
        int i = bid * 256 + tid;
        float4 v = reinterpret_cast<const float4*>(x)[i];
        us4 o = { f2bf(v.x), f2bf(v.y), f2bf(v.z), f2bf(v.w) };
        reinterpret_cast<us4*>(xb)[i] = o;
    } else if (bid < 6144) {
        int j    = (bid - 4096) * 4 + (tid >> 6);
        int lane = tid & 63;
        const float* xl = x + (size_t)(N_ - 1) * D_;
        const float* xj = x + (size_t)j * D_;
        double acc = 0.0;
#pragma unroll
        for (int it = 0; it < 8; ++it) {
            int k = it * 64 + lane;
            acc += (double)xl[k] * (double)xj[k];
        }
#pragma unroll
        for (int m = 32; m >= 1; m >>= 1) acc += __shfl_xor(acc, m, 64);
        if (lane == 0) sim_last[j] = acc;
    } else {
        __shared__ int lh[NC_];
        int b = bid - 6144;                 // 0..31
        if (tid < NC_) lh[tid] = 0;
        __syncthreads();
        atomicAdd(&lh[tg[b * 256 + tid]], 1);
        __syncthreads();
        if (tid < NC_) hist32[b * NC_ + tid] = lh[tid];
    }
}

// ---------- kernel 2: 256x256-tile, 8 waves (2Mx4N), 8-PHASE schedule -------
// T3+T4: per K-tile, 4 phases {ds_read quadrant frags || stage one striped
// unit of tile t+2 into just-freed slots || barrier || lgkm(0) || 16 MFMA}.
// Counted s_waitcnt vmcnt(8) once per tile (8 staging loads/group in flight);
// drains to 0 only before the last tile. One barrier per phase.
// Unit free-schedule (slot last-read -> restage): A-Mh0@ph1->ph2,
// B-Nh0@ph1->ph2, B-Nh1@ph2->ph3, A-Mh1@ph3->ph4. Accumulation order per
// acc element identical to the 2-phase version (kc0 then kc1 per tile).
// 512 threads -> 2 waves/SIMD -> 256-reg cap; peak live ~217 (no spill).
__global__ __launch_bounds__(512, 1) void k_main(const unsigned short* __restrict__ xb,
                                                 const int* __restrict__ tg,
                                                 float* __restrict__ bufP,
                                                 float* __restrict__ bufN) {
    __shared__ alignas(16) unsigned short As[2][256 * 64];   // 64 KiB
    __shared__ alignas(16) unsigned short Bs[2][256 * 64];   // 64 KiB

    const int tid  = threadIdx.x;
    const int w    = tid >> 6;        // wave 0..7
    const int lane = tid & 63;
    const int q    = lane >> 4;
    const int l15  = lane & 15;
    const int wrow = w >> 2;          // 0..1 (128-row half)
    const int wcol = w & 3;           // 0..3 (64-col quarter)

    // XCD-chunked bijective swizzle (528 = 8*66)
    const int bswz = (blockIdx.x & 7) * 66 + (blockIdx.x >> 3);

    // triangular decode: bswz -> (it, jt), it<=jt
    int rem = bswz;
    int it = 0;
    while (rem >= (T32 - it)) { rem -= (T32 - it); it++; }
    const int jt = it + rem;
    const int row0 = it * 256;
    const int col0 = jt * 256;

    // striped stage units (16 KB = 2 loads/thread each). XOR-swizzle: LDS slot
    // sl of row r holds kgroup g = sl ^ (r&7); all bands are 0 mod 8 so
    // r&7 == rr&7. Per-wave dest is uniform-base + lane*16 (linear, m104-safe).
    auto stage_A = [&](int p, int kt, int half) {   // rows {0-63,128-191}+64*half
        const int k0 = kt * BK_;
#pragma unroll
        for (int i = 0; i < 2; ++i) {
            int c  = i * 512 + tid;
            int rr = c >> 3, sl = c & 7;
            int row = (rr & 63) + ((rr >> 6) << 7) + half * 64;
            int g  = sl ^ (rr & 7);
            const unsigned short* ga = xb + (size_t)(row0 + row) * D_ + k0 + g * 8;
            __builtin_amdgcn_global_load_lds(
                (const __attribute__((address_space(1))) void*)ga,
                (__attribute__((address_space(3))) void*)(&As[p][0] + row * 64 + sl * 8),
                16, 0, 0);
        }
    };
    auto stage_B = [&](int p, int kt, int half) {   // rows {0-31,64-95,...}+32*half
        const int k0 = kt * BK_;
#pragma unroll
        for (int i = 0; i < 2; ++i) {
            int c  = i * 512 + tid;
            int rr = c >> 3, sl = c & 7;
            int row = (rr & 31) + ((rr >> 5) << 6) + half * 32;
            int g  = sl ^ (rr & 7);
            const unsigned short* gb = xb + (size_t)(col0 + row) * D_ + k0 + g * 8;
            __builtin_amdgcn_global_load_lds(
                (const __attribute__((address_space(1))) void*)gb,
                (__attribute__((address_space(3))) void*)(&Bs[p][0] + row * 64 + sl * 8),
                16, 0, 0);
        }
    };

    f32x4 acc[8][4];
#pragma unroll
    for (int mi = 0; mi < 8; ++mi)
#pragma unroll
        for (int ni = 0; ni < 4; ++ni)
            acc[mi][ni] = (f32x4){0.f, 0.f, 0.f, 0.f};

    bf16x8 a0[4][2], a1[4][2], b0[2][2], b1[2][2];

#define RD_A(DST, P, MB)                                                      \
    _Pragma("unroll")                                                         \
    for (int mi2 = 0; mi2 < 4; ++mi2)                                         \
        _Pragma("unroll")                                                     \
        for (int kc = 0; kc < 2; ++kc) {                                      \
            int rA = wrow * 128 + ((MB) + mi2) * 16 + l15;                    \
            int sl = (kc * 4 + q) ^ (rA & 7);                                 \
            DST[mi2][kc] = *reinterpret_cast<const bf16x8*>(                  \
                &As[P][0] + rA * 64 + sl * 8);                                \
        }
#define RD_B(DST, P, NB)                                                      \
    _Pragma("unroll")                                                         \
    for (int ni2 = 0; ni2 < 2; ++ni2)                                         \
        _Pragma("unroll")                                                     \
        for (int kc = 0; kc < 2; ++kc) {                                      \
            int rB = wcol * 64 + ((NB) + ni2) * 16 + l15;                     \
            int sl = (kc * 4 + q) ^ (rB & 7);                                 \
            DST[ni2][kc] = *reinterpret_cast<const bf16x8*>(                  \
                &Bs[P][0] + rB * 64 + sl * 8);                                \
        }
#define QMFMA(AF, BF, MB, NB)                                                 \
    _Pragma("unroll")                                                         \
    for (int mi2 = 0; mi2 < 4; ++mi2)                                         \
        _Pragma("unroll")                                                     \
        for (int ni2 = 0; ni2 < 2; ++ni2)                                     \
            _Pragma("unroll")                                                 \
            for (int kc = 0; kc < 2; ++kc)                                    \
                acc[(MB) + mi2][(NB) + ni2] =                                 \
                    __builtin_amdgcn_mfma_f32_16x16x32_bf16(                  \
                        AF[mi2][kc], BF[ni2][kc],                             \
                        acc[(MB) + mi2][(NB) + ni2], 0, 0, 0);

#define PH_BAR()                                                              \
    __builtin_amdgcn_s_barrier();                                             \
    __builtin_amdgcn_sched_barrier(0)
#define PH_PRE()                                                              \
    asm volatile("s_waitcnt lgkmcnt(0)" ::: "memory");                        \
    __builtin_amdgcn_sched_barrier(0);                                        \
    __builtin_amdgcn_s_setprio(1)
#define PH_POST() __builtin_amdgcn_s_setprio(0)

#define GROUP(P, KT2, DS)                                                     \
    do {                                                                      \
        /* ph1 */                                                             \
        PH_BAR();                                                             \
        RD_A(a0, P, 0) RD_B(b0, P, 0)                                         \
        PH_PRE(); QMFMA(a0, b0, 0, 0) PH_POST();                              \
        /* ph2 */                                                             \
        PH_BAR();                                                             \
        RD_B(b1, P, 2)                                                        \
        if (DS) { stage_A(P, KT2, 0); stage_B(P, KT2, 0); }                   \
        PH_PRE(); QMFMA(a0, b1, 0, 2) PH_POST();                              \
        /* ph3 */                                                             \
        PH_BAR();                                                             \
        RD_A(a1, P, 4)                                                        \
        if (DS) stage_B(P, KT2, 1);                                           \
        PH_PRE(); QMFMA(a1, b0, 4, 0) PH_POST();                              \
        /* ph4 */                                                             \
        PH_BAR();                                                             \
        if (DS) stage_A(P, KT2, 1);                                           \
        __builtin_amdgcn_sched_barrier(0);                                    \
        __builtin_amdgcn_s_setprio(1);                                        \
        QMFMA(a1, b1, 4, 2)                                                   \
        __builtin_amdgcn_s_setprio(0);                                        \
    } while (0)

    // prologue: tiles 0 and 1 fully staged (16 loads); tile 0 proven by vmcnt(8)
    stage_A(0, 0, 0); stage_B(0, 0, 0); stage_B(0, 0, 1); stage_A(0, 0, 1);
    stage_A(1, 1, 0); stage_B(1, 1, 0); stage_B(1, 1, 1); stage_A(1, 1, 1);
    asm volatile("s_waitcnt vmcnt(8)" ::: "memory");

    GROUP(0, 2, 1); asm volatile("s_waitcnt vmcnt(8)" ::: "memory");
    GROUP(1, 3, 1); asm volatile("s_waitcnt vmcnt(8)" ::: "memory");
    GROUP(0, 4, 1); asm volatile("s_waitcnt vmcnt(8)" ::: "memory");
    GROUP(1, 5, 1); asm volatile("s_waitcnt vmcnt(8)" ::: "memory");
    GROUP(0, 6, 1); asm volatile("s_waitcnt vmcnt(8)" ::: "memory");
    GROUP(1, 7, 1); asm volatile("s_waitcnt vmcnt(8)" ::: "memory");
    GROUP(0, 9, 0); asm volatile("s_waitcnt vmcnt(0)" ::: "memory");
    GROUP(1, 9, 0);

#undef GROUP
#undef PH_POST
#undef PH_PRE
#undef PH_BAR
#undef QMFMA
#undef RD_B
#undef RD_A

    // ---------------- epilogue (R3/R7-verified, 8-wave) ----------------
    int tC[4];
#pragma unroll
    for (int ni = 0; ni < 4; ++ni)
        tC[ni] = tg[col0 + wcol * 64 + ni * 16 + l15];

    float cps[4], cns[4];
#pragma unroll
    for (int ni = 0; ni < 4; ++ni) { cps[ni] = 0.f; cns[ni] = 0.f; }

    // scr aliases As[0] (tile-6 buffer, dead; staging fully drained by the
    // vmcnt(0) above; last reads of As[0] sealed by tile-7 ph1 barrier).
    float* scr = (float*)As;   // rowP[4][256] | rowN[4][256] | colP[2][256] | colN[2][256]

#pragma unroll
    for (int mi = 0; mi < 8; ++mi) {
        int tRv[4];
#pragma unroll
        for (int r = 0; r < 4; ++r)
            tRv[r] = tg[row0 + wrow * 128 + mi * 16 + q * 4 + r];
        float ps_[4] = {0.f, 0.f, 0.f, 0.f};
        float ns_[4] = {0.f, 0.f, 0.f, 0.f};
#pragma unroll
        for (int ni = 0; ni < 4; ++ni)
#pragma unroll
            for (int r = 0; r < 4; ++r) {
                float s = acc[mi][ni][r];
                bool same = (tRv[r] == tC[ni]);
                float e = __expf(same ? 1.0f - s : s);
                float pe = (same && (s < 1.0f)) ? e : 0.0f;
                float ne = same ? 0.0f : e;
                ps_[r] += pe; ns_[r] += ne;
                cps[ni] += pe; cns[ni] += ne;
            }
#pragma unroll
        for (int r = 0; r < 4; ++r) {
            float p = ps_[r];
            float n = ns_[r];
#pragma unroll
            for (int m = 1; m < 16; m <<= 1) {
                p += __shfl_xor(p, m, 64);
                n += __shfl_xor(n, m, 64);
            }
            if (l15 == 0) {
                int rloc = wrow * 128 + mi * 16 + q * 4 + r;
                scr[wcol * 256 + rloc]        = p;
                scr[1024 + wcol * 256 + rloc] = n;
            }
        }
    }

#pragma unroll
    for (int ni = 0; ni < 4; ++ni) {
        float p = cps[ni];
        float n = cns[ni];
        p += __shfl_xor(p, 16, 64); p += __shfl_xor(p, 32, 64);
        n += __shfl_xor(n, 16, 64); n += __shfl_xor(n, 32, 64);
        if (q == 0) {
            int cloc = wcol * 64 + ni * 16 + l15;
            scr[2048 + wrow * 256 + cloc] = p;
            scr[2560 + wrow * 256 + cloc] = n;
        }
    }
    __syncthreads();

    if (tid < 256) {
        int r = tid;
        size_t off = ((size_t)it * T32 + jt) * 256 + r;
        bufP[off] = scr[r] + scr[256 + r] + scr[512 + r] + scr[768 + r];
        bufN[off] = scr[1024 + r] + scr[1280 + r] + scr[1536 + r] + scr[1792 + r];
    } else if (jt != it) {
        int c = tid - 256;
        size_t off = ((size_t)jt * T32 + it) * 256 + c;
        bufP[off] = scr[2048 + c] + scr[2304 + c];
        bufN[off] = scr[2560 + c] + scr[2816 + c];
    }
}

// ---------- kernel 3: reduce + finalize (64 blocks, atomic-chained) ----------
__global__ __launch_bounds__(256) void k_post(const float* __restrict__ bufP,
                                              const float* __restrict__ bufN,
                                              const int* __restrict__ tg,
                                              const int* __restrict__ hist32,
                                              const double* __restrict__ sim_last,
                                              double* __restrict__ gd,
                                              int* __restrict__ gi,
                                              float* __restrict__ out) {
    __shared__ int lh[NC_];
    __shared__ float sv[256];
    __shared__ double Rd[256], Pd[256], Nd[256];
    __shared__ int Ri[256], Pc[256], Nc[256];
    const int t   = blockIdx.x;       // 0..63
    const int tid = threadIdx.x;

    if (tid < NC_) {
        int a = 0;
#pragma unroll
        for (int b = 0; b < 32; ++b) a += hist32[b * NC_ + tid];
        lh[tid] = a;
    }

    const int half = tid >> 7;        // 0: psum, 1: nsum
    const int r    = tid & 127;
    const int rt   = t >> 1;                    // 256-row tile
    const int r256 = (t & 1) * 128 + r;         // row within tile
    const float* buf  = half ? bufN : bufP;
    const float* base = buf + (size_t)rt * T32 * 256 + r256;
    float s = 0.f;
#pragma unroll
    for (int o = 0; o < T32; ++o) s += base[o * 256];
    sv[tid] = s;
    __syncthreads();

    double rd = 0.0, pd = 0.0, nd = 0.0;
    int ri = 0, pc = 0, nc = 0;
    if (tid < 128) {
        int row = t * 128 + tid;
        bool ok = lh[tg[row]] < N_;
        rd = ok ? (double)(logf(sv[tid]) + logf(sv[128 + tid])) : 0.0;
        ri = ok ? 0 : 1;
        double sl = sim_last[row];
        int tlast = tg[N_ - 1];
        if (tg[row] == tlast) { if (sl < 1.0) { pd = sl; pc = 1; } }
        else                  { nd = sl; nc = 1; }
    }

    Rd[tid] = rd; Ri[tid] = ri;
    Pd[tid] = pd; Pc[tid] = pc;
    Nd[tid] = nd; Nc[tid] = nc;
    __syncthreads();
    for (int st = 128; st >= 1; st >>= 1) {
        if (tid < st) {
            Rd[tid] += Rd[tid + st]; Pd[tid] += Pd[tid + st]; Nd[tid] += Nd[tid + st];
            Ri[tid] += Ri[tid + st]; Pc[tid] += Pc[tid + st]; Nc[tid] += Nc[tid + st];
        }
        __syncthreads();
    }

    if (tid == 0) {
        atomicAdd(&gd[0], Rd[0]);
        atomicAdd(&gd[1], Pd[0]);
        atomicAdd(&gd[2], Nd[0]);
        atomicAdd(&gi[0], Ri[0]);
        atomicAdd(&gi[1], Pc[0]);
        atomicAdd(&gi[2], Nc[0]);
        __threadfence();
        int old = atomicAdd(&gi[3], 1);
        if (old == 63) {
            double A = atomicAdd(&gd[0], 0.0);
            double B = atomicAdd(&gd[1], 0.0);
            double C = atomicAdd(&gd[2], 0.0);
            int U = atomicAdd(&gi[0], 0);
            int V = atomicAdd(&gi[1], 0);
            int Y = atomicAdd(&gi[2], 0);
            out[0] = (float)(A / (double)N_);
            out[1] = (float)U / (float)N_;
            out[2] = (float)(B / (double)V);
            out[3] = (float)(C / (double)Y);
        }
    }
}

extern "C" void kernel_launch(void* const* d_in, const int* in_sizes, int n_in,
                              void* d_out, int out_size, void* d_ws, size_t ws_size,
                              hipStream_t stream) {
    const float* x  = (const float*)d_in[0];
    const int*   tg = (const int*)d_in[1];
    char* ws = (char*)d_ws;

    unsigned short* xb = (unsigned short*)ws;                 // 8 MB
    const size_t XB = (size_t)N_ * D_ * 2;                    // 8388608
    float*  bufP = (float*)(ws + XB);                         // 32*32*256*4 = 1 MB
    float*  bufN = (float*)(ws + XB + (1u << 20));            // 1 MB
    double* sim_last = (double*)(ws + XB + (2u << 20));       // 64 KB
    int*    hist32   = (int*)(ws + XB + (2u << 20) + 65536);  // 16 KB
    double* gd   = (double*)(ws + XB + (2u << 20) + 65536 + 16384);    // 3 doubles
    int*    gi   = (int*)(ws + XB + (2u << 20) + 65536 + 16384 + 64);  // 4 ints

    const int nblk_tri = T32 * (T32 + 1) / 2;                 // 528

    hipLaunchKernelGGL(k_pre, dim3(4096 + 2048 + 32), dim3(256), 0, stream,
                       x, xb, tg, sim_last, hist32, gd, gi);
    hipLaunchKernelGGL(k_main, dim3(nblk_tri), dim3(512), 0, stream, xb, tg, bufP, bufN);
    hipLaunchKernelGGL(k_post, dim3(64), dim3(256), 0, stream,
                       bufP, bufN, tg, hist32, sim_last, gd, gi, (float*)d_out);
}

// Round 11
// 146.514 us; speedup vs baseline: 1.0850x; 1.0850x over previous
//
#include <hip/hip_runtime.h>
#include <math.h>

#define N_ 8192
#define D_ 512
#define NC_ 128
#define T_ 64      // 8192/128 row-tiles
#define BK_ 32     // K-step
#define KSTEPS 16  // 512/32

typedef __attribute__((ext_vector_type(8))) short bf16x8;
typedef __attribute__((ext_vector_type(4))) float f32x4;
typedef __attribute__((ext_vector_type(4))) unsigned short us4;

static __device__ __forceinline__ unsigned short f2bf(float f) {
    union { float f; unsigned u; } c; c.f = f;
    unsigned u = c.u;
    u += 0x7fffu + ((u >> 16) & 1u);   // round-to-nearest-even
    return (unsigned short)(u >> 16);
}

// ---------- kernel 1: convert + last-row fp64 dots + histogram (wide) --------
__global__ __launch_bounds__(256) void k_pre(const float* __restrict__ x,
                                             unsigned short* __restrict__ xb,
                                             const int* __restrict__ tg,
                                             double* __restrict__ sim_last,
                                             int* __restrict__ hist32,
                                             double* __restrict__ gd,
                                             int* __restrict__ gi) {
    const int bid = blockIdx.x;
    const int tid = threadIdx.x;
    if (bid == 0 && tid == 0) {
        atomicExch((unsigned long long*)&gd[0], 0ull);
        atomicExch((unsigned long long*)&gd[1], 0ull);
        atomicExch((unsigned long long*)&gd[2], 0ull);
        atomicExch(&gi[0], 0); atomicExch(&gi[1], 0);
        atomicExch(&gi[2], 0); atomicExch(&gi[3], 0);
    }
    if (bid < 4096) {
        int i = bid * 256 + tid;
        float4 v = reinterpret_cast<const float4*>(x)[i];
        us4 o = { f2bf(v.x), f2bf(v.y), f2bf(v.z), f2bf(v.w) };
        reinterpret_cast<us4*>(xb)[i] = o;
    } else if (bid < 6144) {
        int j    = (bid - 4096) * 4 + (tid >> 6);
        int lane = tid & 63;
        const float* xl = x + (size_t)(N_ - 1) * D_;
        const float* xj = x + (size_t)j * D_;
        double acc = 0.0;
#pragma unroll
        for (int it = 0; it < 8; ++it) {
            int k = it * 64 + lane;
            acc += (double)xl[k] * (double)xj[k];
        }
#pragma unroll
        for (int m = 32; m >= 1; m >>= 1) acc += __shfl_xor(acc, m, 64);
        if (lane == 0) sim_last[j] = acc;
    } else {
        __shared__ int lh[NC_];
        int b = bid - 6144;                 // 0..31
        if (tid < NC_) lh[tid] = 0;
        __syncthreads();
        atomicAdd(&lh[tg[b * 256 + tid]], 1);
        __syncthreads();
        if (tid < NC_) hist32[b * NC_ + tid] = lh[tid];
    }
}

// ---------- kernel 2: symmetric fused bf16 MFMA sim + masked exp partials ----
// grid = 2080 triangular tile-pairs (it<=jt), 128x128 tile, 256 threads.
// UNTESTED CELL of the {wait-discipline x occupancy} matrix:
//   counted-vmcnt 2-deep pipeline (R4's proven +6%) at BK=32 / 32 KiB LDS
//   -> 4 blocks/CU (R2's proven geometry & swizzle), so the per-tile barrier
//   dead time of one block overlaps other blocks' MFMA while loads never
//   drain mid-loop (steady s_waitcnt vmcnt(4) = waits only loads issued two
//   tiles ago; vmcnt hits 0 once, at the last tile).
// Accumulation order = K ascending, identical to R2's refcheck-passed kernel.
__global__ __launch_bounds__(256, 4) void k_main(const unsigned short* __restrict__ xb,
                                                 const int* __restrict__ tg,
                                                 float* __restrict__ bufP,
                                                 float* __restrict__ bufN) {
    __shared__ alignas(16) unsigned short As[2][128 * BK_];   // 16 KiB
    __shared__ alignas(16) unsigned short Bs[2][128 * BK_];   // 16 KiB

    const int tid  = threadIdx.x;
    const int w    = tid >> 6;
    const int lane = tid & 63;
    const int q    = lane >> 4;
    const int l15  = lane & 15;
    const int wrow = w >> 1;      // 0..1
    const int wcol = w & 1;       // 0..1

    // XCD-chunked bijective swizzle (2080 = 8*260)
    const int bswz = (blockIdx.x & 7) * 260 + (blockIdx.x >> 3);

    // triangular decode: bswz -> (it, jt), it<=jt
    int rem = bswz;
    int it = 0;
    while (rem >= (T_ - it)) { rem -= (T_ - it); it++; }
    const int jt = it + rem;
    const int row0 = it * 128;
    const int col0 = jt * 128;

    // stage A(128x32) + B(128x32) of K-tile kt into buffer p: 4 gload_lds/thread.
    // XOR-swizzled source (R2-proven): LDS slot sl (of 4/row) holds kgroup
    // g = sl ^ ((r>>1)&3) -> 2 lanes/bank on ds_read_b128 (free, m136).
    auto stage_tile = [&](int p, int kt) {
        const int k0 = kt * BK_;
#pragma unroll
        for (int itr = 0; itr < 2; ++itr) {
            int slot = itr * 4 + w;          // 0..7
            int gs = slot * 64 + lane;       // 16B-chunk id 0..511
            int r  = gs >> 2;                // row 0..127
            int sl = gs & 3;
            int g  = sl ^ ((r >> 1) & 3);
            const unsigned short* ga = xb + (size_t)(row0 + r) * D_ + k0 + g * 8;
            const unsigned short* gb = xb + (size_t)(col0 + r) * D_ + k0 + g * 8;
            __builtin_amdgcn_global_load_lds(
                (const __attribute__((address_space(1))) void*)ga,
                (__attribute__((address_space(3))) void*)(&As[p][0] + slot * 512),
                16, 0, 0);
            __builtin_amdgcn_global_load_lds(
                (const __attribute__((address_space(1))) void*)gb,
                (__attribute__((address_space(3))) void*)(&Bs[p][0] + slot * 512),
                16, 0, 0);
        }
    };

    f32x4 acc[4][4];
#pragma unroll
    for (int mi = 0; mi < 4; ++mi)
#pragma unroll
        for (int ni = 0; ni < 4; ++ni)
            acc[mi][ni] = (f32x4){0.f, 0.f, 0.f, 0.f};

    // one K-tile: 8 ds_read_b128 -> 16 MFMA
    auto compute_tile = [&](int p) {
        bf16x8 aF[4], bF[4];
#pragma unroll
        for (int mi = 0; mi < 4; ++mi) {
            int rA = wrow * 64 + mi * 16 + l15;
            int sl = q ^ ((rA >> 1) & 3);
            aF[mi] = *reinterpret_cast<const bf16x8*>(&As[p][0] + rA * BK_ + sl * 8);
        }
#pragma unroll
        for (int ni = 0; ni < 4; ++ni) {
            int rB = wcol * 64 + ni * 16 + l15;
            int sl = q ^ ((rB >> 1) & 3);
            bF[ni] = *reinterpret_cast<const bf16x8*>(&Bs[p][0] + rB * BK_ + sl * 8);
        }
        asm volatile("s_waitcnt lgkmcnt(0)" ::: "memory");
        __builtin_amdgcn_sched_barrier(0);   // rule 18: MFMA must not hoist
        __builtin_amdgcn_s_setprio(1);
#pragma unroll
        for (int mi = 0; mi < 4; ++mi)
#pragma unroll
            for (int ni = 0; ni < 4; ++ni)
                acc[mi][ni] = __builtin_amdgcn_mfma_f32_16x16x32_bf16(
                    aF[mi], bF[ni], acc[mi][ni], 0, 0, 0);
        __builtin_amdgcn_s_setprio(0);
    };

#define TILE(P, KS, DOSTAGE, VMN)                                         \
    do {                                                                  \
        asm volatile("s_waitcnt vmcnt(" #VMN ")" ::: "memory");           \
        __builtin_amdgcn_s_barrier();                                     \
        __builtin_amdgcn_sched_barrier(0);                                \
        compute_tile(P);                                                  \
        __builtin_amdgcn_s_barrier();                                     \
        __builtin_amdgcn_sched_barrier(0);                                \
        if (DOSTAGE) stage_tile(P, (KS) + 2);                             \
    } while (0)

    // prologue: two K-tiles in flight (8 gload_lds/thread outstanding)
    stage_tile(0, 0);
    stage_tile(1, 1);

    TILE(0, 0, 1, 4);
    TILE(1, 1, 1, 4);
    TILE(0, 2, 1, 4);
    TILE(1, 3, 1, 4);
    TILE(0, 4, 1, 4);
    TILE(1, 5, 1, 4);
    TILE(0, 6, 1, 4);
    TILE(1, 7, 1, 4);
    TILE(0, 8, 1, 4);
    TILE(1, 9, 1, 4);
    TILE(0, 10, 1, 4);
    TILE(1, 11, 1, 4);
    TILE(0, 12, 1, 4);
    TILE(1, 13, 1, 4);
    TILE(0, 14, 0, 4);
    TILE(1, 15, 0, 0);
#undef TILE

    // ---------------- epilogue (R4-verified) ----------------
    int tC[4];
#pragma unroll
    for (int ni = 0; ni < 4; ++ni)
        tC[ni] = tg[col0 + wcol * 64 + ni * 16 + l15];

    float ps[4][4], ns[4][4];
    float cps[4], cns[4];
    int tR[4][4];
#pragma unroll
    for (int mi = 0; mi < 4; ++mi)
#pragma unroll
        for (int r = 0; r < 4; ++r) {
            ps[mi][r] = 0.f; ns[mi][r] = 0.f;
            tR[mi][r] = tg[row0 + wrow * 64 + mi * 16 + q * 4 + r];
        }
#pragma unroll
    for (int ni = 0; ni < 4; ++ni) { cps[ni] = 0.f; cns[ni] = 0.f; }

#pragma unroll
    for (int mi = 0; mi < 4; ++mi)
#pragma unroll
        for (int ni = 0; ni < 4; ++ni)
#pragma unroll
            for (int r = 0; r < 4; ++r) {
                float s = acc[mi][ni][r];
                bool same = (tR[mi][r] == tC[ni]);
                float e = __expf(same ? 1.0f - s : s);
                float pe = (same && (s < 1.0f)) ? e : 0.0f;
                float ne = same ? 0.0f : e;
                ps[mi][r] += pe; ns[mi][r] += ne;
                cps[ni]   += pe; cns[ni]   += ne;
            }

    // combine wave halves through LDS scratch = As[0] (4 KiB of 16 KiB;
    // last compute used buffer 1 -> disjoint; all As[0] reads sealed by the
    // tile-15 leading barrier which every wave has passed)
    float* scr = (float*)As;         // [0:256)=rowP, [256:512)=rowN,
                                     // [512:768)=colP, [768:1024)=colN
#pragma unroll
    for (int mi = 0; mi < 4; ++mi)
#pragma unroll
        for (int r = 0; r < 4; ++r) {
            float p = ps[mi][r];
            float n = ns[mi][r];
#pragma unroll
            for (int m = 1; m < 16; m <<= 1) {
                p += __shfl_xor(p, m, 64);
                n += __shfl_xor(n, m, 64);
            }
            if (l15 == 0) {
                int rloc = wrow * 64 + mi * 16 + q * 4 + r;
                scr[wcol * 128 + rloc]       = p;
                scr[256 + wcol * 128 + rloc] = n;
            }
        }

#pragma unroll
    for (int ni = 0; ni < 4; ++ni) {
        float p = cps[ni];
        float n = cns[ni];
        p += __shfl_xor(p, 16, 64); p += __shfl_xor(p, 32, 64);
        n += __shfl_xor(n, 16, 64); n += __shfl_xor(n, 32, 64);
        if (q == 0) {
            int cloc = wcol * 64 + ni * 16 + l15;
            scr[512 + wrow * 128 + cloc] = p;
            scr[768 + wrow * 128 + cloc] = n;
        }
    }
    __syncthreads();

    if (tid < 128) {
        int r = tid;
        size_t off = ((size_t)it * T_ + jt) * 128 + r;
        bufP[off] = scr[r]       + scr[128 + r];
        bufN[off] = scr[256 + r] + scr[384 + r];
    } else if (jt != it) {
        int c = tid - 128;
        size_t off = ((size_t)jt * T_ + it) * 128 + c;
        bufP[off] = scr[512 + c] + scr[640 + c];
        bufN[off] = scr[768 + c] + scr[896 + c];
    }
}

// ---------- kernel 3: reduce + finalize (64 blocks, atomic-chained) ----------
__global__ __launch_bounds__(256) void k_post(const float* __restrict__ bufP,
                                              const float* __restrict__ bufN,
                                              const int* __restrict__ tg,
                                              const int* __restrict__ hist32,
                                              const double* __restrict__ sim_last,
                                              double* __restrict__ gd,
                                              int* __restrict__ gi,
                                              float* __restrict__ out) {
    __shared__ int lh[NC_];
    __shared__ float sv[256];
    __shared__ double Rd[256], Pd[256], Nd[256];
    __shared__ int Ri[256], Pc[256], Nc[256];
    const int t   = blockIdx.x;       // 0..63
    const int tid = threadIdx.x;

    if (tid < NC_) {
        int a = 0;
#pragma unroll
        for (int b = 0; b < 32; ++b) a += hist32[b * NC_ + tid];
        lh[tid] = a;
    }

    const int half = tid >> 7;        // 0: psum, 1: nsum
    const int r    = tid & 127;
    const float* buf  = half ? bufN : bufP;
    const float* base = buf + (size_t)t * T_ * 128 + r;
    float s = 0.f;
#pragma unroll
    for (int o = 0; o < T_; ++o) s += base[o * 128];
    sv[tid] = s;
    __syncthreads();

    double rd = 0.0, pd = 0.0, nd = 0.0;
    int ri = 0, pc = 0, nc = 0;
    if (tid < 128) {
        int row = t * 128 + tid;
        bool ok = lh[tg[row]] < N_;
        rd = ok ? (double)(logf(sv[tid]) + logf(sv[128 + tid])) : 0.0;
        ri = ok ? 0 : 1;
        double sl = sim_last[row];
        int tlast = tg[N_ - 1];
        if (tg[row] == tlast) { if (sl < 1.0) { pd = sl; pc = 1; } }
        else                  { nd = sl; nc = 1; }
    }

    Rd[tid] = rd; Ri[tid] = ri;
    Pd[tid] = pd; Pc[tid] = pc;
    Nd[tid] = nd; Nc[tid] = nc;
    __syncthreads();
    for (int st = 128; st >= 1; st >>= 1) {
        if (tid < st) {
            Rd[tid] += Rd[tid + st]; Pd[tid] += Pd[tid + st]; Nd[tid] += Nd[tid + st];
            Ri[tid] += Ri[tid + st]; Pc[tid] += Pc[tid + st]; Nc[tid] += Nc[tid + st];
        }
        __syncthreads();
    }

    if (tid == 0) {
        atomicAdd(&gd[0], Rd[0]);
        atomicAdd(&gd[1], Pd[0]);
        atomicAdd(&gd[2], Nd[0]);
        atomicAdd(&gi[0], Ri[0]);
        atomicAdd(&gi[1], Pc[0]);
        atomicAdd(&gi[2], Nc[0]);
        __threadfence();
        int old = atomicAdd(&gi[3], 1);
        if (old == 63) {
            double A = atomicAdd(&gd[0], 0.0);
            double B = atomicAdd(&gd[1], 0.0);
            double C = atomicAdd(&gd[2], 0.0);
            int U = atomicAdd(&gi[0], 0);
            int V = atomicAdd(&gi[1], 0);
            int Y = atomicAdd(&gi[2], 0);
            out[0] = (float)(A / (double)N_);
            out[1] = (float)U / (float)N_;
            out[2] = (float)(B / (double)V);
            out[3] = (float)(C / (double)Y);
        }
    }
}

extern "C" void kernel_launch(void* const* d_in, const int* in_sizes, int n_in,
                              void* d_out, int out_size, void* d_ws, size_t ws_size,
                              hipStream_t stream) {
    const float* x  = (const float*)d_in[0];
    const int*   tg = (const int*)d_in[1];
    char* ws = (char*)d_ws;

    unsigned short* xb = (unsigned short*)ws;                 // 8 MB
    const size_t XB = (size_t)N_ * D_ * 2;                    // 8388608
    float*  bufP = (float*)(ws + XB);                         // 2 MB
    float*  bufN = (float*)(ws + XB + 2097152);               // 2 MB
    double* sim_last = (double*)(ws + XB + 4194304);          // 64 KB
    int*    hist32   = (int*)(ws + XB + 4194304 + 65536);     // 16 KB
    double* gd   = (double*)(ws + XB + 4194304 + 65536 + 16384);      // 3 doubles
    int*    gi   = (int*)(ws + XB + 4194304 + 65536 + 16384 + 64);    // 4 ints

    const int nblk_tri = T_ * (T_ + 1) / 2;                   // 2080

    hipLaunchKernelGGL(k_pre, dim3(4096 + 2048 + 32), dim3(256), 0, stream,
                       x, xb, tg, sim_last, hist32, gd, gi);
    hipLaunchKernelGGL(k_main, dim3(nblk_tri), dim3(256), 0, stream, xb, tg, bufP, bufN);
    hipLaunchKernelGGL(k_post, dim3(64), dim3(256), 0, stream,
                       bufP, bufN, tg, hist32, sim_last, gd, gi, (float*)d_out);
}